// Round 2
// baseline (136.259 us; speedup 1.0000x reference)
//
#include <hip/hip_runtime.h>

#define N_PTS  2048
#define BATCH  64
#define NSLICE 16
#define SLICE  (N_PTS / NSLICE)   // 128 search pts per block
#define P      8                  // query points per thread (8*256 = all 2048)
#define BLK    256
#define QSPLIT 8                  // K2 query-dimension split

static_assert(P * BLK == N_PTS, "each block covers all queries of its (b,dir)");
static_assert(SLICE <= BLK, "one staging point per thread");

// order-preserving float<->int key for signed-int atomicMin
// (squared distances can round slightly negative; plain bit-compare would
//  mis-order negatives, this transform is exact & monotone for all floats)
__device__ __forceinline__ int fkey(float v) {
    int b = __float_as_int(v);
    return b >= 0 ? b : b ^ 0x7fffffff;
}
__device__ __forceinline__ float funkey(int b) {
    return __int_as_float(b >= 0 ? b : b ^ 0x7fffffff);
}

// ---------------------------------------------------------------------------
// K1: partial chamfer mins.  grid (NSLICE=16, BATCH, 2), block 256.
//
// Round-1 post-mortem: K1=63us vs VALU floor 34us + LDS-return 26us -- the
// pipes serialize at 2.3 waves/SIMD (real VALU issue ~50%; the "101%"
// VALUBusy is the gfx94x 4-cyc formula on a SIMD-32 part).  Fix: NSLICE=16
// gives 2048 blocks = 8 blocks/CU; __launch_bounds__(256,8) pins VGPR<=64
// (round-1 compiled to 60; psq[] array dropped, recomputed from pm in the
// epilogue) so all 8 blocks are resident = 8 waves/SIMD.  LDS bytes/pair
// are slicing-invariant (20B/P = 2.5B), so target = max(34,26)us ~ 42us.
// Jet term is fused here (dir==0,s==0 blocks own all 2048 p in registers),
// so K2 is a pure merge.
// ---------------------------------------------------------------------------
template <bool ATOMIC>
__global__ __launch_bounds__(BLK, 8) void chamfer_partial(
        const float4* __restrict__ p,
        const float4* __restrict__ q,
        float* __restrict__ ws,
        float* __restrict__ out) {
    __shared__ float4 sQ[SLICE];        // 2 KB
    __shared__ float4 sQs4[SLICE / 4];  // 512 B: |q|^2 packed 4 per float4
    __shared__ float4 wacc[BLK / 64];

    const int tid = threadIdx.x;
    const int s   = blockIdx.x;
    const int b   = blockIdx.y;
    const int dir = blockIdx.z;
    const float4* __restrict__ A  = dir ? q : p;   // query side
    const float4* __restrict__ Bm = dir ? p : q;   // search side
    const float4* __restrict__ Ab = A  + (size_t)b * N_PTS;
    const float4* __restrict__ Bb = Bm + (size_t)b * N_PTS + s * SLICE;

    if (tid < SLICE) {   // stage the slice, coalesced
        const float4 v = Bb[tid];
        sQ[tid] = v;
        ((float*)sQs4)[tid] = v.x * v.x + v.y * v.y + v.z * v.z + v.w * v.w;
    }
    __syncthreads();

    float4 pm[P];   // -2 * query point
    float  mn[P];
#pragma unroll
    for (int k = 0; k < P; ++k) {
        const float4 pv = Ab[tid + k * BLK];
        pm[k] = make_float4(-2.0f * pv.x, -2.0f * pv.y, -2.0f * pv.z, -2.0f * pv.w);
        mn[k] = 3.4e38f;
    }

#define CHAMFER_STEP(JJ, QS)                          \
    {                                                 \
        const float4 qv = sQ[(JJ)];                   \
        _Pragma("unroll")                             \
        for (int k = 0; k < P; ++k) {                 \
            float t = fmaf(pm[k].x, qv.x, (QS));      \
            t = fmaf(pm[k].y, qv.y, t);               \
            t = fmaf(pm[k].z, qv.z, t);               \
            t = fmaf(pm[k].w, qv.w, t);               \
            mn[k] = fminf(mn[k], t);                  \
        }                                             \
    }

    for (int j = 0; j < SLICE; j += 4) {
        const float4 qs4 = sQs4[j >> 2];
        CHAMFER_STEP(j + 0, qs4.x)
        CHAMFER_STEP(j + 1, qs4.y)
        CHAMFER_STEP(j + 2, qs4.z)
        CHAMFER_STEP(j + 3, qs4.w)
    }
#undef CHAMFER_STEP

    // epilogue: fold |p|^2 back in (recomputed from pm: pm.pm = 4 p.p)
    if (ATOMIC) {
        int* wi = (int*)ws + ((size_t)dir * BATCH + b) * N_PTS;
#pragma unroll
        for (int k = 0; k < P; ++k) {
            const float4 m = pm[k];
            const float psq = 0.25f * (m.x * m.x + m.y * m.y + m.z * m.z + m.w * m.w);
            atomicMin(wi + tid + k * BLK, fkey(mn[k] + psq));
        }
    } else {
        float* wf = ws + (((size_t)dir * BATCH + b) * NSLICE + s) * N_PTS;
#pragma unroll
        for (int k = 0; k < P; ++k) {
            const float4 m = pm[k];
            const float psq = 0.25f * (m.x * m.x + m.y * m.y + m.z * m.z + m.w * m.w);
            wf[tid + k * BLK] = mn[k] + psq;
        }
    }

    // ---- fused jet term: the (dir==0, s==0) block of each batch owns all
    // 2048 p-queries in registers (sum p = -0.5 * sum pm); stream q from L2.
    if (dir == 0 && s == 0) {
        float ax = 0.f, ay = 0.f, az = 0.f, aw = 0.f;
#pragma unroll
        for (int k = 0; k < P; ++k) {
            ax += pm[k].x; ay += pm[k].y; az += pm[k].z; aw += pm[k].w;
        }
        ax *= -0.5f; ay *= -0.5f; az *= -0.5f; aw *= -0.5f;
        const float4* __restrict__ Qb = q + (size_t)b * N_PTS;
        for (int j = tid; j < N_PTS; j += BLK) {
            const float4 qv = Qb[j];
            ax -= qv.x; ay -= qv.y; az -= qv.z; aw -= qv.w;
        }
#pragma unroll
        for (int off = 32; off > 0; off >>= 1) {
            ax += __shfl_down(ax, off, 64);
            ay += __shfl_down(ay, off, 64);
            az += __shfl_down(az, off, 64);
            aw += __shfl_down(aw, off, 64);
        }
        const int lane = tid & 63;
        const int wid  = tid >> 6;
        if (lane == 0) wacc[wid] = make_float4(ax, ay, az, aw);
        __syncthreads();
        if (tid == 0) {
            float dx = 0.f, dy = 0.f, dz = 0.f, dw = 0.f;
#pragma unroll
            for (int w = 0; w < BLK / 64; ++w) {
                dx += wacc[w].x; dy += wacc[w].y; dz += wacc[w].z; dw += wacc[w].w;
            }
            atomicAdd(out, dx * dx + dy * dy + dz * dz + dw * dw);
        }
    }
}

// ---------------------------------------------------------------------------
// K2: merge slice partials + sum chamfer.  grid (QSPLIT=8, BATCH) = 512
// blocks, one query per thread -> ~4us (round-1's 64-block K2 was ~20us).
// ---------------------------------------------------------------------------
template <bool ATOMIC>
__global__ __launch_bounds__(BLK) void chamfer_reduce(
        const float* __restrict__ ws,
        float* __restrict__ out) {
    __shared__ float r[BLK / 64];
    const int tid = threadIdx.x;
    const int qi  = blockIdx.x * BLK + tid;
    const int b   = blockIdx.y;

    float acc = 0.0f;
#pragma unroll
    for (int dir = 0; dir < 2; ++dir) {
        if (ATOMIC) {
            const int* wi = (const int*)ws + ((size_t)dir * BATCH + b) * N_PTS;
            acc += funkey(wi[qi]);
        } else {
            const float* wf = ws + ((size_t)dir * BATCH + b) * NSLICE * N_PTS + qi;
            float m = wf[0];
#pragma unroll
            for (int s2 = 1; s2 < NSLICE; ++s2)
                m = fminf(m, wf[(size_t)s2 * N_PTS]);
            acc += m;
        }
    }

#pragma unroll
    for (int off = 32; off > 0; off >>= 1) acc += __shfl_down(acc, off, 64);
    const int lane = tid & 63;
    const int wid  = tid >> 6;
    if (lane == 0) r[wid] = acc;
    __syncthreads();
    if (tid == 0) {
        float sc = 0.f;
#pragma unroll
        for (int w = 0; w < BLK / 64; ++w) sc += r[w];
        atomicAdd(out, sc);
    }
}

extern "C" void kernel_launch(void* const* d_in, const int* in_sizes, int n_in,
                              void* d_out, int out_size, void* d_ws, size_t ws_size,
                              hipStream_t stream) {
    const float4* p = (const float4*)d_in[0];
    const float4* q = (const float4*)d_in[1];
    float* out = (float*)d_out;
    float* ws  = (float*)d_ws;

    hipMemsetAsync(out, 0, sizeof(float), stream);

    const size_t need_plain = (size_t)2 * BATCH * NSLICE * N_PTS * sizeof(float); // 16 MB
    if (ws_size >= need_plain) {
        // deterministic plain-store path
        chamfer_partial<false><<<dim3(NSLICE, BATCH, 2), BLK, 0, stream>>>(p, q, ws, out);
        chamfer_reduce<false><<<dim3(QSPLIT, BATCH), BLK, 0, stream>>>(ws, out);
    } else {
        // compact 1 MB path: init keys to large positive, atomicMin merge
        hipMemsetAsync(ws, 0x7F, (size_t)2 * BATCH * N_PTS * sizeof(float), stream);
        chamfer_partial<true><<<dim3(NSLICE, BATCH, 2), BLK, 0, stream>>>(p, q, ws, out);
        chamfer_reduce<true><<<dim3(QSPLIT, BATCH), BLK, 0, stream>>>(ws, out);
    }
}